// Round 5
// baseline (870.270 us; speedup 1.0000x reference)
//
#include <hip/hip_runtime.h>
#include <hip/hip_bf16.h>
#include <math.h>

#define N_NODES 50000
#define E_EDGES 800000
#define NFEAT 16
#define EFEAT 8
#define HID 32
#define HEADS 4
#define HC 128

__device__ __forceinline__ float lrelu(float v) { return v > 0.f ? v : 0.2f * v; }

// ---- K1: h = x @ W ; alpha_src/dst = einsum(h, aS/aD) per head ----
template<int FIN, int HOUT, int H>
__global__ void k1_gemm_alpha(const float* __restrict__ x, const float* __restrict__ W,
                              const float* __restrict__ aS, const float* __restrict__ aD,
                              float* __restrict__ hout, float* __restrict__ asrc,
                              float* __restrict__ adst, int n_nodes)
{
    constexpr int GROUPS = 256 / HOUT;
    constexpr int NPT = 4;
    constexpr int NPB = GROUPS * NPT;
    __shared__ float xs[NPB * (FIN + 1)];
    const int tid = threadIdx.x;
    const int nb0 = blockIdx.x * NPB;
    for (int idx = tid; idx < NPB * FIN; idx += 256) {
        int node = idx / FIN, k = idx % FIN;
        int gn = nb0 + node;
        xs[node * (FIN + 1) + k] = (gn < n_nodes) ? x[gn * FIN + k] : 0.f;
    }
    __syncthreads();
    const int c = tid % HOUT;
    const int g = tid / HOUT;
    const int head = c / HID;
    const int cc = c % HID;
    const float aSv = aS[head * HID + cc];
    const float aDv = aD[head * HID + cc];
    float acc[NPT];
#pragma unroll
    for (int i = 0; i < NPT; i++) acc[i] = 0.f;
    for (int k = 0; k < FIN; k++) {
        float w = W[k * HOUT + c];
#pragma unroll
        for (int i = 0; i < NPT; i++)
            acc[i] += w * xs[(g * NPT + i) * (FIN + 1) + k];
    }
#pragma unroll
    for (int i = 0; i < NPT; i++) {
        int n = nb0 + g * NPT + i;
        bool ok = (n < n_nodes);
        float h = acc[i];
        if (ok) hout[n * HOUT + c] = h;
        float pa = h * aSv, pb = h * aDv;
#pragma unroll
        for (int off = 16; off >= 1; off >>= 1) {
            pa += __shfl_xor(pa, off, 32);
            pb += __shfl_xor(pb, off, 32);
        }
        if (ok && cc == 0) { asrc[n * H + head] = pa; adst[n * H + head] = pb; }
    }
}

// ---- CSR build: histogram -> single-block scan -> scatter ----
__global__ void kc_count(const int* __restrict__ ei1, int* __restrict__ cnt)
{
    int e = blockIdx.x * 256 + threadIdx.x;
    if (e >= E_EDGES) return;
    atomicAdd(&cnt[ei1[e]], 1);
}

__global__ __launch_bounds__(1024) void kc_scan(const int* __restrict__ cnt,
                                                int* __restrict__ rowptr,
                                                int* __restrict__ cur)
{
    __shared__ int tsum[1024];
    const int t = threadIdx.x;
    const int CH = (N_NODES + 1023) / 1024;  // 49
    int lo = t * CH, hi = lo + CH;
    if (hi > N_NODES) hi = N_NODES;
    int s = 0;
    for (int i = lo; i < hi; i++) s += cnt[i];
    tsum[t] = s;
    __syncthreads();
    for (int off = 1; off < 1024; off <<= 1) {
        int v = (t >= off) ? tsum[t - off] : 0;
        __syncthreads();
        tsum[t] += v;
        __syncthreads();
    }
    int run = (t == 0) ? 0 : tsum[t - 1];
    for (int i = lo; i < hi; i++) {
        rowptr[i] = run;
        cur[i] = run;
        run += cnt[i];
    }
}

__global__ void kc_scatter(const int* __restrict__ ei0, const int* __restrict__ ei1,
                           int* __restrict__ cur, int* __restrict__ srcs)
{
    int e = blockIdx.x * 256 + threadIdx.x;
    if (e >= E_EDGES) return;
    int pos = atomicAdd(&cur[ei1[e]], 1);
    srcs[pos] = ei0[e];
}

// ---- fused aggregation: online segment-softmax + weighted sum + bias (+ELU) ----
// TPE = H*C/2 threads per node; each thread owns 2 channels (float2).
// 4-way batched loads break the dependent-load latency chain; the online
// updates stay strictly sequential (bit-identical to the 1-way version).
template<int H, int C, bool DO_ELU>
__global__ __launch_bounds__(256) void k_aggr(
    const float* __restrict__ asrc, const float* __restrict__ adst,
    const float* __restrict__ hbuf, const int* __restrict__ rowptr,
    const int* __restrict__ deg, const int* __restrict__ srcs,
    const float* __restrict__ b, float* __restrict__ outp)
{
    constexpr int HCL = H * C;
    constexpr int TPE = HCL / 2;
    constexpr int NPB = 256 / TPE;
    const int t = threadIdx.x % TPE;
    const int n = blockIdx.x * NPB + threadIdx.x / TPE;
    if (n >= N_NODES) return;
    const int c0 = 2 * t;
    const int head = c0 / C;
    const float adstv = adst[n * H + head];
    // init with self-loop
    float m = lrelu(asrc[n * H + head] + adstv);
    float ssum = 1.f;
    float2 hv = *(const float2*)(hbuf + (size_t)n * HCL + c0);
    float a0 = hv.x, a1 = hv.y;
    const int base = rowptr[n];
    const int dg = deg[n];
    int i = 0;
    for (; i + 4 <= dg; i += 4) {
        int s0 = srcs[base + i + 0];
        int s1 = srcs[base + i + 1];
        int s2 = srcs[base + i + 2];
        int s3 = srcs[base + i + 3];
        float sc0 = lrelu(asrc[s0 * H + head] + adstv);
        float sc1 = lrelu(asrc[s1 * H + head] + adstv);
        float sc2 = lrelu(asrc[s2 * H + head] + adstv);
        float sc3 = lrelu(asrc[s3 * H + head] + adstv);
        float2 h0 = *(const float2*)(hbuf + (size_t)s0 * HCL + c0);
        float2 h1 = *(const float2*)(hbuf + (size_t)s1 * HCL + c0);
        float2 h2 = *(const float2*)(hbuf + (size_t)s2 * HCL + c0);
        float2 h3v = *(const float2*)(hbuf + (size_t)s3 * HCL + c0);
        float sc[4] = {sc0, sc1, sc2, sc3};
        float2 hh[4] = {h0, h1, h2, h3v};
#pragma unroll
        for (int u = 0; u < 4; u++) {
            float scv = sc[u];
            float ex;
            if (scv > m) {
                float r = __expf(m - scv);
                ssum *= r; a0 *= r; a1 *= r;
                m = scv;
                ex = 1.f;
            } else {
                ex = __expf(scv - m);
            }
            ssum += ex;
            a0 += ex * hh[u].x;
            a1 += ex * hh[u].y;
        }
    }
    for (; i < dg; i++) {
        int s = srcs[base + i];
        float sc = lrelu(asrc[s * H + head] + adstv);
        float2 hs = *(const float2*)(hbuf + (size_t)s * HCL + c0);
        float ex;
        if (sc > m) {
            float r = __expf(m - sc);
            ssum *= r; a0 *= r; a1 *= r;
            m = sc;
            ex = 1.f;
        } else {
            ex = __expf(sc - m);
        }
        ssum += ex;
        a0 += ex * hs.x;
        a1 += ex * hs.y;
    }
    float inv = 1.f / (ssum + 1e-16f);
    float v0 = a0 * inv + b[c0];
    float v1 = a1 * inv + b[c0 + 1];
    if (DO_ELU) {
        v0 = v0 > 0.f ? v0 : __expf(v0) - 1.f;
        v1 = v1 > 0.f ? v1 : __expf(v1) - 1.f;
    }
    *(float2*)(outp + (size_t)n * HCL + c0) = make_float2(v0, v1);
}

// ---- K5: per-edge MLP 72 -> 32 -> 32 -> 1, softplus ----
// 2 edges per thread: each LDS weight read feeds 2 FMAs (LDS-BW bound fix).
__global__ __launch_bounds__(256) void k5_mlp(
                       const int* __restrict__ ei0, const int* __restrict__ ei1,
                       const float* __restrict__ h3, const float* __restrict__ ea,
                       const float* __restrict__ Wm1, const float* __restrict__ bm1,
                       const float* __restrict__ Wm2, const float* __restrict__ bm2,
                       const float* __restrict__ Wm3, const float* __restrict__ bm3,
                       float* __restrict__ out)
{
    __shared__ float w1[72 * 32], w2[32 * 32], w3s[32], b1s[32], b2s[32];
    __shared__ float b3s;
    const int tid = threadIdx.x;
    for (int i = tid; i < 72 * 32; i += 256) w1[i] = Wm1[i];
    for (int i = tid; i < 32 * 32; i += 256) w2[i] = Wm2[i];
    if (tid < 32) { w3s[tid] = Wm3[tid]; b1s[tid] = bm1[tid]; b2s[tid] = bm2[tid]; }
    if (tid == 0) b3s = bm3[0];
    __syncthreads();
    const int e0 = blockIdx.x * 512 + tid;
    const int e1 = e0 + 256;
    if (e0 >= E_EDGES) return;
    const bool has1 = (e1 < E_EDGES);
    int sA = ei0[e0], dA = ei1[e0];
    int sB = has1 ? ei0[e1] : sA;
    int dB = has1 ? ei1[e1] : dA;

    const float4* hsa = (const float4*)(h3 + (size_t)sA * 32);
    const float4* hda = (const float4*)(h3 + (size_t)dA * 32);
    const float4* hsb = (const float4*)(h3 + (size_t)sB * 32);
    const float4* hdb = (const float4*)(h3 + (size_t)dB * 32);
    const float4* eva = (const float4*)(ea + (size_t)e0 * 8);
    const float4* evb = (const float4*)(ea + (size_t)(has1 ? e1 : e0) * 8);

    float za[32], zb[32];
#pragma unroll
    for (int j = 0; j < 32; j++) { za[j] = b1s[j]; zb[j] = b1s[j]; }

#pragma unroll
    for (int kq = 0; kq < 8; kq++) {
        float4 va = hsa[kq];
        float4 vb = hsb[kq];
        const float* wrow = &w1[(kq * 4) * 32];
#pragma unroll
        for (int j = 0; j < 32; j++) { float w = wrow[0 * 32 + j]; za[j] += va.x * w; zb[j] += vb.x * w; }
#pragma unroll
        for (int j = 0; j < 32; j++) { float w = wrow[1 * 32 + j]; za[j] += va.y * w; zb[j] += vb.y * w; }
#pragma unroll
        for (int j = 0; j < 32; j++) { float w = wrow[2 * 32 + j]; za[j] += va.z * w; zb[j] += vb.z * w; }
#pragma unroll
        for (int j = 0; j < 32; j++) { float w = wrow[3 * 32 + j]; za[j] += va.w * w; zb[j] += vb.w * w; }
    }
#pragma unroll
    for (int kq = 0; kq < 8; kq++) {
        float4 va = hda[kq];
        float4 vb = hdb[kq];
        const float* wrow = &w1[(32 + kq * 4) * 32];
#pragma unroll
        for (int j = 0; j < 32; j++) { float w = wrow[0 * 32 + j]; za[j] += va.x * w; zb[j] += vb.x * w; }
#pragma unroll
        for (int j = 0; j < 32; j++) { float w = wrow[1 * 32 + j]; za[j] += va.y * w; zb[j] += vb.y * w; }
#pragma unroll
        for (int j = 0; j < 32; j++) { float w = wrow[2 * 32 + j]; za[j] += va.z * w; zb[j] += vb.z * w; }
#pragma unroll
        for (int j = 0; j < 32; j++) { float w = wrow[3 * 32 + j]; za[j] += va.w * w; zb[j] += vb.w * w; }
    }
#pragma unroll
    for (int kq = 0; kq < 2; kq++) {
        float4 va = eva[kq];
        float4 vb = evb[kq];
        const float* wrow = &w1[(64 + kq * 4) * 32];
#pragma unroll
        for (int j = 0; j < 32; j++) { float w = wrow[0 * 32 + j]; za[j] += va.x * w; zb[j] += vb.x * w; }
#pragma unroll
        for (int j = 0; j < 32; j++) { float w = wrow[1 * 32 + j]; za[j] += va.y * w; zb[j] += vb.y * w; }
#pragma unroll
        for (int j = 0; j < 32; j++) { float w = wrow[2 * 32 + j]; za[j] += va.z * w; zb[j] += vb.z * w; }
#pragma unroll
        for (int j = 0; j < 32; j++) { float w = wrow[3 * 32 + j]; za[j] += va.w * w; zb[j] += vb.w * w; }
    }
#pragma unroll
    for (int j = 0; j < 32; j++) {
        za[j] = za[j] > 0.f ? za[j] : 0.f;
        zb[j] = zb[j] > 0.f ? zb[j] : 0.f;
    }

    float z3a = b3s, z3b = b3s;
#pragma unroll
    for (int j = 0; j < 32; j++) {
        float aa = b2s[j], ab = b2s[j];
#pragma unroll
        for (int k = 0; k < 32; k++) {
            float w = w2[k * 32 + j];
            aa += za[k] * w;
            ab += zb[k] * w;
        }
        float w3v = w3s[j];
        z3a += (aa > 0.f ? aa : 0.f) * w3v;
        z3b += (ab > 0.f ? ab : 0.f) * w3v;
    }
    out[e0] = (z3a > 20.f) ? z3a : log1pf(__expf(z3a));
    if (has1) out[e1] = (z3b > 20.f) ? z3b : log1pf(__expf(z3b));
}

extern "C" void kernel_launch(void* const* d_in, const int* in_sizes, int n_in,
                              void* d_out, int out_size, void* d_ws, size_t ws_size,
                              hipStream_t stream)
{
    const float* x   = (const float*)d_in[0];
    const int*   ei  = (const int*)d_in[1];
    const int*   ei0 = ei;
    const int*   ei1 = ei + E_EDGES;
    const float* ea  = (const float*)d_in[2];
    const float* W1  = (const float*)d_in[3];
    const float* aS1 = (const float*)d_in[4];
    const float* aD1 = (const float*)d_in[5];
    const float* b1  = (const float*)d_in[6];
    const float* W2  = (const float*)d_in[7];
    const float* aS2 = (const float*)d_in[8];
    const float* aD2 = (const float*)d_in[9];
    const float* b2  = (const float*)d_in[10];
    const float* W3  = (const float*)d_in[11];
    const float* aS3 = (const float*)d_in[12];
    const float* aD3 = (const float*)d_in[13];
    const float* b3  = (const float*)d_in[14];
    const float* Wm1 = (const float*)d_in[15];
    const float* bm1 = (const float*)d_in[16];
    const float* Wm2 = (const float*)d_in[17];
    const float* bm2 = (const float*)d_in[18];
    const float* Wm3 = (const float*)d_in[19];
    const float* bm3 = (const float*)d_in[20];

    float* ws = (float*)d_ws;
    float* bufA = ws;                                    // [N,128] h of current layer
    float* bufB = bufA + (size_t)N_NODES * HC;           // [N,128] layer output
    float* asrc = bufB + (size_t)N_NODES * HC;           // [N,4]
    float* adst = asrc + (size_t)N_NODES * HEADS;        // [N,4]
    int* cnt    = (int*)(adst + (size_t)N_NODES * HEADS);// [N] in-degree (no self-loop)
    int* rowptr = cnt + N_NODES;                         // [N]
    int* cur    = rowptr + N_NODES;                      // [N]
    int* srcs   = cur + N_NODES;                         // [E]

    float* out = (float*)d_out;

    // ---------------- CSR build (once; shared by all 3 layers) ----------------
    hipMemsetAsync(cnt, 0, (size_t)N_NODES * sizeof(int), stream);
    kc_count<<<(E_EDGES + 255) / 256, 256, 0, stream>>>(ei1, cnt);
    kc_scan<<<1, 1024, 0, stream>>>(cnt, rowptr, cur);
    kc_scatter<<<(E_EDGES + 255) / 256, 256, 0, stream>>>(ei0, ei1, cur, srcs);

    // ---------------- Layer 1: x[N,16] -> bufB[N,128] (ELU) ----------------
    k1_gemm_alpha<NFEAT, HC, HEADS><<<(N_NODES + 7) / 8, 256, 0, stream>>>(
        x, W1, aS1, aD1, bufA, asrc, adst, N_NODES);
    k_aggr<HEADS, HID, true><<<(N_NODES + 3) / 4, 256, 0, stream>>>(
        asrc, adst, bufA, rowptr, cnt, srcs, b1, bufB);

    // ---------------- Layer 2: bufB[N,128] -> bufB[N,128] (ELU) ----------------
    k1_gemm_alpha<HC, HC, HEADS><<<(N_NODES + 7) / 8, 256, 0, stream>>>(
        bufB, W2, aS2, aD2, bufA, asrc, adst, N_NODES);
    k_aggr<HEADS, HID, true><<<(N_NODES + 3) / 4, 256, 0, stream>>>(
        asrc, adst, bufA, rowptr, cnt, srcs, b2, bufB);

    // ---------------- Layer 3: bufB[N,128] -> bufB[N,32] (no act, H=1) ----------------
    k1_gemm_alpha<HC, HID, 1><<<(N_NODES + 31) / 32, 256, 0, stream>>>(
        bufB, W3, aS3, aD3, bufA, asrc, adst, N_NODES);
    k_aggr<1, HID, false><<<(N_NODES + 15) / 16, 256, 0, stream>>>(
        asrc, adst, bufA, rowptr, cnt, srcs, b3, bufB);

    // ---------------- Edge MLP on ORIGINAL edges (512 edges per 256-thread block) ----------------
    k5_mlp<<<(E_EDGES + 511) / 512, 256, 0, stream>>>(
        ei0, ei1, bufB, ea, Wm1, bm1, Wm2, bm2, Wm3, bm3, out);
}

// Round 6
// 569.475 us; speedup vs baseline: 1.5282x; 1.5282x over previous
//
#include <hip/hip_runtime.h>
#include <hip/hip_bf16.h>
#include <math.h>

#define N_NODES 50000
#define E_EDGES 800000
#define NFEAT 16
#define EFEAT 8
#define HID 32
#define HEADS 4
#define HC 128

__device__ __forceinline__ float lrelu(float v) { return v > 0.f ? v : 0.2f * v; }

// ---- K1: h = x @ W ; alpha_src/dst = einsum(h, aS/aD) per head ----
template<int FIN, int HOUT, int H>
__global__ void k1_gemm_alpha(const float* __restrict__ x, const float* __restrict__ W,
                              const float* __restrict__ aS, const float* __restrict__ aD,
                              float* __restrict__ hout, float* __restrict__ asrc,
                              float* __restrict__ adst, int n_nodes)
{
    constexpr int GROUPS = 256 / HOUT;
    constexpr int NPT = 4;
    constexpr int NPB = GROUPS * NPT;
    __shared__ float xs[NPB * (FIN + 1)];
    const int tid = threadIdx.x;
    const int nb0 = blockIdx.x * NPB;
    for (int idx = tid; idx < NPB * FIN; idx += 256) {
        int node = idx / FIN, k = idx % FIN;
        int gn = nb0 + node;
        xs[node * (FIN + 1) + k] = (gn < n_nodes) ? x[gn * FIN + k] : 0.f;
    }
    __syncthreads();
    const int c = tid % HOUT;
    const int g = tid / HOUT;
    const int head = c / HID;
    const int cc = c % HID;
    const float aSv = aS[head * HID + cc];
    const float aDv = aD[head * HID + cc];
    float acc[NPT];
#pragma unroll
    for (int i = 0; i < NPT; i++) acc[i] = 0.f;
    for (int k = 0; k < FIN; k++) {
        float w = W[k * HOUT + c];
#pragma unroll
        for (int i = 0; i < NPT; i++)
            acc[i] += w * xs[(g * NPT + i) * (FIN + 1) + k];
    }
#pragma unroll
    for (int i = 0; i < NPT; i++) {
        int n = nb0 + g * NPT + i;
        bool ok = (n < n_nodes);
        float h = acc[i];
        if (ok) hout[n * HOUT + c] = h;
        float pa = h * aSv, pb = h * aDv;
#pragma unroll
        for (int off = 16; off >= 1; off >>= 1) {
            pa += __shfl_xor(pa, off, 32);
            pb += __shfl_xor(pb, off, 32);
        }
        if (ok && cc == 0) { asrc[n * H + head] = pa; adst[n * H + head] = pb; }
    }
}

// ---- CSR build: histogram -> single-block scan -> scatter ----
__global__ void kc_count(const int* __restrict__ ei1, int* __restrict__ cnt)
{
    int e = blockIdx.x * 256 + threadIdx.x;
    if (e >= E_EDGES) return;
    atomicAdd(&cnt[ei1[e]], 1);
}

__global__ __launch_bounds__(1024) void kc_scan(const int* __restrict__ cnt,
                                                int* __restrict__ rowptr,
                                                int* __restrict__ cur)
{
    __shared__ int tsum[1024];
    const int t = threadIdx.x;
    const int CH = (N_NODES + 1023) / 1024;  // 49
    int lo = t * CH, hi = lo + CH;
    if (hi > N_NODES) hi = N_NODES;
    int s = 0;
    for (int i = lo; i < hi; i++) s += cnt[i];
    tsum[t] = s;
    __syncthreads();
    for (int off = 1; off < 1024; off <<= 1) {
        int v = (t >= off) ? tsum[t - off] : 0;
        __syncthreads();
        tsum[t] += v;
        __syncthreads();
    }
    int run = (t == 0) ? 0 : tsum[t - 1];
    for (int i = lo; i < hi; i++) {
        rowptr[i] = run;
        cur[i] = run;
        run += cnt[i];
    }
}

__global__ void kc_scatter(const int* __restrict__ ei0, const int* __restrict__ ei1,
                           int* __restrict__ cur, int* __restrict__ srcs)
{
    int e = blockIdx.x * 256 + threadIdx.x;
    if (e >= E_EDGES) return;
    int pos = atomicAdd(&cur[ei1[e]], 1);
    srcs[pos] = ei0[e];
}

// ---- fused aggregation: online segment-softmax + weighted sum + bias (+ELU) ----
template<int H, int C, bool DO_ELU>
__global__ __launch_bounds__(256) void k_aggr(
    const float* __restrict__ asrc, const float* __restrict__ adst,
    const float* __restrict__ hbuf, const int* __restrict__ rowptr,
    const int* __restrict__ deg, const int* __restrict__ srcs,
    const float* __restrict__ b, float* __restrict__ outp)
{
    constexpr int HCL = H * C;
    constexpr int TPE = HCL / 2;
    constexpr int NPB = 256 / TPE;
    const int t = threadIdx.x % TPE;
    const int n = blockIdx.x * NPB + threadIdx.x / TPE;
    if (n >= N_NODES) return;
    const int c0 = 2 * t;
    const int head = c0 / C;
    const float adstv = adst[n * H + head];
    // init with self-loop
    float m = lrelu(asrc[n * H + head] + adstv);
    float ssum = 1.f;
    float2 hv = *(const float2*)(hbuf + (size_t)n * HCL + c0);
    float a0 = hv.x, a1 = hv.y;
    const int base = rowptr[n];
    const int dg = deg[n];
    int i = 0;
    for (; i + 4 <= dg; i += 4) {
        int s0 = srcs[base + i + 0];
        int s1 = srcs[base + i + 1];
        int s2 = srcs[base + i + 2];
        int s3 = srcs[base + i + 3];
        float sc0 = lrelu(asrc[s0 * H + head] + adstv);
        float sc1 = lrelu(asrc[s1 * H + head] + adstv);
        float sc2 = lrelu(asrc[s2 * H + head] + adstv);
        float sc3 = lrelu(asrc[s3 * H + head] + adstv);
        float2 h0 = *(const float2*)(hbuf + (size_t)s0 * HCL + c0);
        float2 h1 = *(const float2*)(hbuf + (size_t)s1 * HCL + c0);
        float2 h2 = *(const float2*)(hbuf + (size_t)s2 * HCL + c0);
        float2 h3v = *(const float2*)(hbuf + (size_t)s3 * HCL + c0);
        float sc[4] = {sc0, sc1, sc2, sc3};
        float2 hh[4] = {h0, h1, h2, h3v};
#pragma unroll
        for (int u = 0; u < 4; u++) {
            float scv = sc[u];
            float ex;
            if (scv > m) {
                float r = __expf(m - scv);
                ssum *= r; a0 *= r; a1 *= r;
                m = scv;
                ex = 1.f;
            } else {
                ex = __expf(scv - m);
            }
            ssum += ex;
            a0 += ex * hh[u].x;
            a1 += ex * hh[u].y;
        }
    }
    for (; i < dg; i++) {
        int s = srcs[base + i];
        float sc = lrelu(asrc[s * H + head] + adstv);
        float2 hs = *(const float2*)(hbuf + (size_t)s * HCL + c0);
        float ex;
        if (sc > m) {
            float r = __expf(m - sc);
            ssum *= r; a0 *= r; a1 *= r;
            m = sc;
            ex = 1.f;
        } else {
            ex = __expf(sc - m);
        }
        ssum += ex;
        a0 += ex * hs.x;
        a1 += ex * hs.y;
    }
    float inv = 1.f / (ssum + 1e-16f);
    float v0 = a0 * inv + b[c0];
    float v1 = a1 * inv + b[c0 + 1];
    if (DO_ELU) {
        v0 = v0 > 0.f ? v0 : __expf(v0) - 1.f;
        v1 = v1 > 0.f ? v1 : __expf(v1) - 1.f;
    }
    *(float2*)(outp + (size_t)n * HCL + c0) = make_float2(v0, v1);
}

// ---- K5a: node-level precompute for MLP layer 1 ----
// P[n][0:32]  = h3[n] @ W1a  (Wm1 rows 0..31)
// P[n][32:64] = h3[n] @ W1b  (Wm1 rows 32..63)
__global__ __launch_bounds__(256) void k5a_precomp(
    const float* __restrict__ h3, const float* __restrict__ Wm1,
    float* __restrict__ P)
{
    __shared__ float w[64 * 32];      // rows 0..63 of Wm1
    __shared__ float hsh[16][33];
    const int tid = threadIdx.x;
    for (int i = tid; i < 64 * 32; i += 256) w[i] = Wm1[i];
    const int nb0 = blockIdx.x * 16;
    for (int idx = tid; idx < 16 * 32; idx += 256) {
        int node = idx / 32, k = idx % 32;
        int gn = nb0 + node;
        hsh[node][k] = (gn < N_NODES) ? h3[gn * 32 + k] : 0.f;
    }
    __syncthreads();
    const int c = tid % 64;           // output channel 0..63
    const int part = c / 32;          // 0 -> W1a, 1 -> W1b
    const int j = c % 32;
    for (int ln = tid / 64; ln < 16; ln += 4) {
        int gn = nb0 + ln;
        if (gn >= N_NODES) break;
        float sum = 0.f;
#pragma unroll
        for (int k = 0; k < 32; k++)
            sum += hsh[ln][k] * w[(part * 32 + k) * 32 + j];
        P[(size_t)gn * 64 + c] = sum;
    }
}

// ---- K5b: per-edge MLP using precomputed P ----
// z1 = relu(P[s][0:32] + P[d][32:64] + ea @ W1c + b1); z2; z3; softplus.
__global__ __launch_bounds__(256) void k5b_mlp(
                       const int* __restrict__ ei0, const int* __restrict__ ei1,
                       const float* __restrict__ P, const float* __restrict__ ea,
                       const float* __restrict__ Wm1, const float* __restrict__ bm1,
                       const float* __restrict__ Wm2, const float* __restrict__ bm2,
                       const float* __restrict__ Wm3, const float* __restrict__ bm3,
                       float* __restrict__ out)
{
    __shared__ float w1c[8 * 32], w2[32 * 32], w3s[32], b1s[32], b2s[32];
    __shared__ float b3s;
    const int tid = threadIdx.x;
    if (tid < 8 * 32) w1c[tid] = Wm1[64 * 32 + tid];
    for (int i = tid; i < 32 * 32; i += 256) w2[i] = Wm2[i];
    if (tid < 32) { w3s[tid] = Wm3[tid]; b1s[tid] = bm1[tid]; b2s[tid] = bm2[tid]; }
    if (tid == 0) b3s = bm3[0];
    __syncthreads();
    const int e = blockIdx.x * 256 + tid;
    if (e >= E_EDGES) return;
    const int s = ei0[e], d = ei1[e];

    float z1[32];
#pragma unroll
    for (int j = 0; j < 32; j++) z1[j] = b1s[j];

    // edge_attr contribution (8x32 matmul)
    const float4* eav = (const float4*)(ea + (size_t)e * 8);
#pragma unroll
    for (int kq = 0; kq < 2; kq++) {
        float4 v = eav[kq];
        const float* wrow = &w1c[(kq * 4) * 32];
#pragma unroll
        for (int j = 0; j < 32; j++) z1[j] += v.x * wrow[0 * 32 + j];
#pragma unroll
        for (int j = 0; j < 32; j++) z1[j] += v.y * wrow[1 * 32 + j];
#pragma unroll
        for (int j = 0; j < 32; j++) z1[j] += v.z * wrow[2 * 32 + j];
#pragma unroll
        for (int j = 0; j < 32; j++) z1[j] += v.w * wrow[3 * 32 + j];
    }
    // node contributions: elementwise adds of precomputed partials
    const float4* ps = (const float4*)(P + (size_t)s * 64);
    const float4* pd = (const float4*)(P + (size_t)d * 64 + 32);
#pragma unroll
    for (int q = 0; q < 8; q++) {
        float4 a = ps[q];
        float4 b = pd[q];
        z1[4 * q + 0] += a.x + b.x;
        z1[4 * q + 1] += a.y + b.y;
        z1[4 * q + 2] += a.z + b.z;
        z1[4 * q + 3] += a.w + b.w;
    }
#pragma unroll
    for (int j = 0; j < 32; j++) z1[j] = z1[j] > 0.f ? z1[j] : 0.f;

    float z3 = b3s;
#pragma unroll
    for (int j = 0; j < 32; j++) {
        float a = b2s[j];
#pragma unroll
        for (int k = 0; k < 32; k++) a += z1[k] * w2[k * 32 + j];
        z3 += (a > 0.f ? a : 0.f) * w3s[j];
    }
    out[e] = (z3 > 20.f) ? z3 : log1pf(__expf(z3));
}

extern "C" void kernel_launch(void* const* d_in, const int* in_sizes, int n_in,
                              void* d_out, int out_size, void* d_ws, size_t ws_size,
                              hipStream_t stream)
{
    const float* x   = (const float*)d_in[0];
    const int*   ei  = (const int*)d_in[1];
    const int*   ei0 = ei;
    const int*   ei1 = ei + E_EDGES;
    const float* ea  = (const float*)d_in[2];
    const float* W1  = (const float*)d_in[3];
    const float* aS1 = (const float*)d_in[4];
    const float* aD1 = (const float*)d_in[5];
    const float* b1  = (const float*)d_in[6];
    const float* W2  = (const float*)d_in[7];
    const float* aS2 = (const float*)d_in[8];
    const float* aD2 = (const float*)d_in[9];
    const float* b2  = (const float*)d_in[10];
    const float* W3  = (const float*)d_in[11];
    const float* aS3 = (const float*)d_in[12];
    const float* aD3 = (const float*)d_in[13];
    const float* b3  = (const float*)d_in[14];
    const float* Wm1 = (const float*)d_in[15];
    const float* bm1 = (const float*)d_in[16];
    const float* Wm2 = (const float*)d_in[17];
    const float* bm2 = (const float*)d_in[18];
    const float* Wm3 = (const float*)d_in[19];
    const float* bm3 = (const float*)d_in[20];

    float* ws = (float*)d_ws;
    float* bufA = ws;                                    // [N,128] h / later P[N,64]
    float* bufB = bufA + (size_t)N_NODES * HC;           // [N,128] layer output
    float* asrc = bufB + (size_t)N_NODES * HC;           // [N,4]
    float* adst = asrc + (size_t)N_NODES * HEADS;        // [N,4]
    int* cnt    = (int*)(adst + (size_t)N_NODES * HEADS);// [N] in-degree (no self-loop)
    int* rowptr = cnt + N_NODES;                         // [N]
    int* cur    = rowptr + N_NODES;                      // [N]
    int* srcs   = cur + N_NODES;                         // [E]

    float* out = (float*)d_out;

    // ---------------- CSR build (once; shared by all 3 layers) ----------------
    hipMemsetAsync(cnt, 0, (size_t)N_NODES * sizeof(int), stream);
    kc_count<<<(E_EDGES + 255) / 256, 256, 0, stream>>>(ei1, cnt);
    kc_scan<<<1, 1024, 0, stream>>>(cnt, rowptr, cur);
    kc_scatter<<<(E_EDGES + 255) / 256, 256, 0, stream>>>(ei0, ei1, cur, srcs);

    // ---------------- Layer 1: x[N,16] -> bufB[N,128] (ELU) ----------------
    k1_gemm_alpha<NFEAT, HC, HEADS><<<(N_NODES + 7) / 8, 256, 0, stream>>>(
        x, W1, aS1, aD1, bufA, asrc, adst, N_NODES);
    k_aggr<HEADS, HID, true><<<(N_NODES + 3) / 4, 256, 0, stream>>>(
        asrc, adst, bufA, rowptr, cnt, srcs, b1, bufB);

    // ---------------- Layer 2: bufB[N,128] -> bufB[N,128] (ELU) ----------------
    k1_gemm_alpha<HC, HC, HEADS><<<(N_NODES + 7) / 8, 256, 0, stream>>>(
        bufB, W2, aS2, aD2, bufA, asrc, adst, N_NODES);
    k_aggr<HEADS, HID, true><<<(N_NODES + 3) / 4, 256, 0, stream>>>(
        asrc, adst, bufA, rowptr, cnt, srcs, b2, bufB);

    // ---------------- Layer 3: bufB[N,128] -> bufB[N,32] (no act, H=1) ----------------
    k1_gemm_alpha<HC, HID, 1><<<(N_NODES + 31) / 32, 256, 0, stream>>>(
        bufB, W3, aS3, aD3, bufA, asrc, adst, N_NODES);
    k_aggr<1, HID, false><<<(N_NODES + 15) / 16, 256, 0, stream>>>(
        asrc, adst, bufA, rowptr, cnt, srcs, b3, bufB);

    // ---------------- Edge MLP: node precompute, then per-edge ----------------
    // bufA is free now; reuse as P[N,64]
    float* P = bufA;
    k5a_precomp<<<(N_NODES + 15) / 16, 256, 0, stream>>>(bufB, Wm1, P);
    k5b_mlp<<<(E_EDGES + 255) / 256, 256, 0, stream>>>(
        ei0, ei1, P, ea, Wm1, bm1, Wm2, bm2, Wm3, bm3, out);
}

// Round 7
// 468.973 us; speedup vs baseline: 1.8557x; 1.2143x over previous
//
#include <hip/hip_runtime.h>
#include <hip/hip_bf16.h>
#include <math.h>

#define N_NODES 50000
#define E_EDGES 800000
#define NFEAT 16
#define EFEAT 8
#define HID 32
#define HEADS 4
#define HC 128
#define SCAN_NB ((N_NODES + 255) / 256)   // 196

__device__ __forceinline__ float lrelu(float v) { return v > 0.f ? v : 0.2f * v; }

// ---- K1: h = x @ W ; alpha_src/dst = einsum(h, aS/aD) per head ----
template<int FIN, int HOUT, int H>
__global__ void k1_gemm_alpha(const float* __restrict__ x, const float* __restrict__ W,
                              const float* __restrict__ aS, const float* __restrict__ aD,
                              float* __restrict__ hout, float* __restrict__ asrc,
                              float* __restrict__ adst, int n_nodes)
{
    constexpr int GROUPS = 256 / HOUT;
    constexpr int NPT = 4;
    constexpr int NPB = GROUPS * NPT;
    __shared__ float xs[NPB * (FIN + 1)];
    const int tid = threadIdx.x;
    const int nb0 = blockIdx.x * NPB;
    for (int idx = tid; idx < NPB * FIN; idx += 256) {
        int node = idx / FIN, k = idx % FIN;
        int gn = nb0 + node;
        xs[node * (FIN + 1) + k] = (gn < n_nodes) ? x[gn * FIN + k] : 0.f;
    }
    __syncthreads();
    const int c = tid % HOUT;
    const int g = tid / HOUT;
    const int head = c / HID;
    const int cc = c % HID;
    const float aSv = aS[head * HID + cc];
    const float aDv = aD[head * HID + cc];
    float acc[NPT];
#pragma unroll
    for (int i = 0; i < NPT; i++) acc[i] = 0.f;
    for (int k = 0; k < FIN; k++) {
        float w = W[k * HOUT + c];
#pragma unroll
        for (int i = 0; i < NPT; i++)
            acc[i] += w * xs[(g * NPT + i) * (FIN + 1) + k];
    }
#pragma unroll
    for (int i = 0; i < NPT; i++) {
        int n = nb0 + g * NPT + i;
        bool ok = (n < n_nodes);
        float h = acc[i];
        if (ok) hout[n * HOUT + c] = h;
        float pa = h * aSv, pb = h * aDv;
#pragma unroll
        for (int off = 16; off >= 1; off >>= 1) {
            pa += __shfl_xor(pa, off, 32);
            pb += __shfl_xor(pb, off, 32);
        }
        if (ok && cc == 0) { asrc[n * H + head] = pa; adst[n * H + head] = pb; }
    }
}

// ---- CSR build: histogram -> 3-phase scan -> scatter ----
__global__ void kc_count(const int* __restrict__ ei1, int* __restrict__ cnt)
{
    int e = blockIdx.x * 256 + threadIdx.x;
    if (e >= E_EDGES) return;
    atomicAdd(&cnt[ei1[e]], 1);
}

__global__ __launch_bounds__(256) void kc_blocksum(const int* __restrict__ cnt,
                                                   int* __restrict__ bsum)
{
    __shared__ int sd[256];
    const int tid = threadIdx.x;
    int i = blockIdx.x * 256 + tid;
    int v = (i < N_NODES) ? cnt[i] : 0;
    sd[tid] = v;
    __syncthreads();
    for (int off = 128; off >= 1; off >>= 1) {
        if (tid < off) sd[tid] += sd[tid + off];
        __syncthreads();
    }
    if (tid == 0) bsum[blockIdx.x] = sd[0];
}

__global__ __launch_bounds__(256) void kc_scanbsum(const int* __restrict__ bsum,
                                                   int* __restrict__ bofs)
{
    __shared__ int sd[256];
    const int tid = threadIdx.x;
    int v = (tid < SCAN_NB) ? bsum[tid] : 0;
    sd[tid] = v;
    __syncthreads();
    for (int off = 1; off < 256; off <<= 1) {
        int u = (tid >= off) ? sd[tid - off] : 0;
        __syncthreads();
        sd[tid] += u;
        __syncthreads();
    }
    // exclusive offset for block tid
    if (tid < SCAN_NB) bofs[tid] = sd[tid] - v;
}

__global__ __launch_bounds__(256) void kc_apply(const int* __restrict__ cnt,
                                                const int* __restrict__ bofs,
                                                int* __restrict__ rowptr,
                                                int* __restrict__ cur)
{
    __shared__ int sd[256];
    const int tid = threadIdx.x;
    int i = blockIdx.x * 256 + tid;
    int v = (i < N_NODES) ? cnt[i] : 0;
    sd[tid] = v;
    __syncthreads();
    for (int off = 1; off < 256; off <<= 1) {
        int u = (tid >= off) ? sd[tid - off] : 0;
        __syncthreads();
        sd[tid] += u;
        __syncthreads();
    }
    int excl = sd[tid] - v + bofs[blockIdx.x];
    if (i < N_NODES) { rowptr[i] = excl; cur[i] = excl; }
}

__global__ void kc_scatter(const int* __restrict__ ei0, const int* __restrict__ ei1,
                           int* __restrict__ cur, int* __restrict__ srcs)
{
    int e = blockIdx.x * 256 + threadIdx.x;
    if (e >= E_EDGES) return;
    int pos = atomicAdd(&cur[ei1[e]], 1);
    srcs[pos] = ei0[e];
}

// ---- fused aggregation: online segment-softmax + weighted sum + bias (+ELU) ----
template<int H, int C, bool DO_ELU>
__global__ __launch_bounds__(256) void k_aggr(
    const float* __restrict__ asrc, const float* __restrict__ adst,
    const float* __restrict__ hbuf, const int* __restrict__ rowptr,
    const int* __restrict__ deg, const int* __restrict__ srcs,
    const float* __restrict__ b, float* __restrict__ outp)
{
    constexpr int HCL = H * C;
    constexpr int TPE = HCL / 2;
    constexpr int NPB = 256 / TPE;
    const int t = threadIdx.x % TPE;
    const int n = blockIdx.x * NPB + threadIdx.x / TPE;
    if (n >= N_NODES) return;
    const int c0 = 2 * t;
    const int head = c0 / C;
    const float adstv = adst[n * H + head];
    // init with self-loop
    float m = lrelu(asrc[n * H + head] + adstv);
    float ssum = 1.f;
    float2 hv = *(const float2*)(hbuf + (size_t)n * HCL + c0);
    float a0 = hv.x, a1 = hv.y;
    const int base = rowptr[n];
    const int dg = deg[n];
    int i = 0;
    for (; i + 4 <= dg; i += 4) {
        int s0 = srcs[base + i + 0];
        int s1 = srcs[base + i + 1];
        int s2 = srcs[base + i + 2];
        int s3 = srcs[base + i + 3];
        float sc0 = lrelu(asrc[s0 * H + head] + adstv);
        float sc1 = lrelu(asrc[s1 * H + head] + adstv);
        float sc2 = lrelu(asrc[s2 * H + head] + adstv);
        float sc3 = lrelu(asrc[s3 * H + head] + adstv);
        float2 h0 = *(const float2*)(hbuf + (size_t)s0 * HCL + c0);
        float2 h1 = *(const float2*)(hbuf + (size_t)s1 * HCL + c0);
        float2 h2 = *(const float2*)(hbuf + (size_t)s2 * HCL + c0);
        float2 h3v = *(const float2*)(hbuf + (size_t)s3 * HCL + c0);
        float sc[4] = {sc0, sc1, sc2, sc3};
        float2 hh[4] = {h0, h1, h2, h3v};
#pragma unroll
        for (int u = 0; u < 4; u++) {
            float scv = sc[u];
            float ex;
            if (scv > m) {
                float r = __expf(m - scv);
                ssum *= r; a0 *= r; a1 *= r;
                m = scv;
                ex = 1.f;
            } else {
                ex = __expf(scv - m);
            }
            ssum += ex;
            a0 += ex * hh[u].x;
            a1 += ex * hh[u].y;
        }
    }
    for (; i < dg; i++) {
        int s = srcs[base + i];
        float sc = lrelu(asrc[s * H + head] + adstv);
        float2 hs = *(const float2*)(hbuf + (size_t)s * HCL + c0);
        float ex;
        if (sc > m) {
            float r = __expf(m - sc);
            ssum *= r; a0 *= r; a1 *= r;
            m = sc;
            ex = 1.f;
        } else {
            ex = __expf(sc - m);
        }
        ssum += ex;
        a0 += ex * hs.x;
        a1 += ex * hs.y;
    }
    float inv = 1.f / (ssum + 1e-16f);
    float v0 = a0 * inv + b[c0];
    float v1 = a1 * inv + b[c0 + 1];
    if (DO_ELU) {
        v0 = v0 > 0.f ? v0 : __expf(v0) - 1.f;
        v1 = v1 > 0.f ? v1 : __expf(v1) - 1.f;
    }
    *(float2*)(outp + (size_t)n * HCL + c0) = make_float2(v0, v1);
}

// ---- K5a: node-level precompute for MLP layer 1 ----
__global__ __launch_bounds__(256) void k5a_precomp(
    const float* __restrict__ h3, const float* __restrict__ Wm1,
    float* __restrict__ P)
{
    __shared__ float w[64 * 32];      // rows 0..63 of Wm1
    __shared__ float hsh[16][33];
    const int tid = threadIdx.x;
    for (int i = tid; i < 64 * 32; i += 256) w[i] = Wm1[i];
    const int nb0 = blockIdx.x * 16;
    for (int idx = tid; idx < 16 * 32; idx += 256) {
        int node = idx / 32, k = idx % 32;
        int gn = nb0 + node;
        hsh[node][k] = (gn < N_NODES) ? h3[gn * 32 + k] : 0.f;
    }
    __syncthreads();
    const int c = tid % 64;           // output channel 0..63
    const int part = c / 32;          // 0 -> W1a, 1 -> W1b
    const int j = c % 32;
    for (int ln = tid / 64; ln < 16; ln += 4) {
        int gn = nb0 + ln;
        if (gn >= N_NODES) break;
        float sum = 0.f;
#pragma unroll
        for (int k = 0; k < 32; k++)
            sum += hsh[ln][k] * w[(part * 32 + k) * 32 + j];
        P[(size_t)gn * 64 + c] = sum;
    }
}

// ---- K5b: per-edge MLP using precomputed P ----
__global__ __launch_bounds__(256) void k5b_mlp(
                       const int* __restrict__ ei0, const int* __restrict__ ei1,
                       const float* __restrict__ P, const float* __restrict__ ea,
                       const float* __restrict__ Wm1, const float* __restrict__ bm1,
                       const float* __restrict__ Wm2, const float* __restrict__ bm2,
                       const float* __restrict__ Wm3, const float* __restrict__ bm3,
                       float* __restrict__ out)
{
    __shared__ float w1c[8 * 32], w2[32 * 32], w3s[32], b1s[32], b2s[32];
    __shared__ float b3s;
    const int tid = threadIdx.x;
    if (tid < 8 * 32) w1c[tid] = Wm1[64 * 32 + tid];
    for (int i = tid; i < 32 * 32; i += 256) w2[i] = Wm2[i];
    if (tid < 32) { w3s[tid] = Wm3[tid]; b1s[tid] = bm1[tid]; b2s[tid] = bm2[tid]; }
    if (tid == 0) b3s = bm3[0];
    __syncthreads();
    const int e = blockIdx.x * 256 + tid;
    if (e >= E_EDGES) return;
    const int s = ei0[e], d = ei1[e];

    float z1[32];
#pragma unroll
    for (int j = 0; j < 32; j++) z1[j] = b1s[j];

    // edge_attr contribution (8x32 matmul)
    const float4* eav = (const float4*)(ea + (size_t)e * 8);
#pragma unroll
    for (int kq = 0; kq < 2; kq++) {
        float4 v = eav[kq];
        const float* wrow = &w1c[(kq * 4) * 32];
#pragma unroll
        for (int j = 0; j < 32; j++) z1[j] += v.x * wrow[0 * 32 + j];
#pragma unroll
        for (int j = 0; j < 32; j++) z1[j] += v.y * wrow[1 * 32 + j];
#pragma unroll
        for (int j = 0; j < 32; j++) z1[j] += v.z * wrow[2 * 32 + j];
#pragma unroll
        for (int j = 0; j < 32; j++) z1[j] += v.w * wrow[3 * 32 + j];
    }
    // node contributions: elementwise adds of precomputed partials
    const float4* ps = (const float4*)(P + (size_t)s * 64);
    const float4* pd = (const float4*)(P + (size_t)d * 64 + 32);
#pragma unroll
    for (int q = 0; q < 8; q++) {
        float4 a = ps[q];
        float4 b = pd[q];
        z1[4 * q + 0] += a.x + b.x;
        z1[4 * q + 1] += a.y + b.y;
        z1[4 * q + 2] += a.z + b.z;
        z1[4 * q + 3] += a.w + b.w;
    }
#pragma unroll
    for (int j = 0; j < 32; j++) z1[j] = z1[j] > 0.f ? z1[j] : 0.f;

    float z3 = b3s;
#pragma unroll
    for (int j = 0; j < 32; j++) {
        float a = b2s[j];
#pragma unroll
        for (int k = 0; k < 32; k++) a += z1[k] * w2[k * 32 + j];
        z3 += (a > 0.f ? a : 0.f) * w3s[j];
    }
    out[e] = (z3 > 20.f) ? z3 : log1pf(__expf(z3));
}

extern "C" void kernel_launch(void* const* d_in, const int* in_sizes, int n_in,
                              void* d_out, int out_size, void* d_ws, size_t ws_size,
                              hipStream_t stream)
{
    const float* x   = (const float*)d_in[0];
    const int*   ei  = (const int*)d_in[1];
    const int*   ei0 = ei;
    const int*   ei1 = ei + E_EDGES;
    const float* ea  = (const float*)d_in[2];
    const float* W1  = (const float*)d_in[3];
    const float* aS1 = (const float*)d_in[4];
    const float* aD1 = (const float*)d_in[5];
    const float* b1  = (const float*)d_in[6];
    const float* W2  = (const float*)d_in[7];
    const float* aS2 = (const float*)d_in[8];
    const float* aD2 = (const float*)d_in[9];
    const float* b2  = (const float*)d_in[10];
    const float* W3  = (const float*)d_in[11];
    const float* aS3 = (const float*)d_in[12];
    const float* aD3 = (const float*)d_in[13];
    const float* b3  = (const float*)d_in[14];
    const float* Wm1 = (const float*)d_in[15];
    const float* bm1 = (const float*)d_in[16];
    const float* Wm2 = (const float*)d_in[17];
    const float* bm2 = (const float*)d_in[18];
    const float* Wm3 = (const float*)d_in[19];
    const float* bm3 = (const float*)d_in[20];

    float* ws = (float*)d_ws;
    float* bufA = ws;                                    // [N,128] h / later P[N,64]
    float* bufB = bufA + (size_t)N_NODES * HC;           // [N,128] layer output
    float* asrc = bufB + (size_t)N_NODES * HC;           // [N,4]
    float* adst = asrc + (size_t)N_NODES * HEADS;        // [N,4]
    int* cnt    = (int*)(adst + (size_t)N_NODES * HEADS);// [N] in-degree (no self-loop)
    int* rowptr = cnt + N_NODES;                         // [N]
    int* cur    = rowptr + N_NODES;                      // [N]
    int* srcs   = cur + N_NODES;                         // [E]
    int* bsum   = srcs + E_EDGES;                        // [SCAN_NB]
    int* bofs   = bsum + 256;                            // [SCAN_NB]

    float* out = (float*)d_out;

    // ---------------- CSR build (once; shared by all 3 layers) ----------------
    hipMemsetAsync(cnt, 0, (size_t)N_NODES * sizeof(int), stream);
    kc_count<<<(E_EDGES + 255) / 256, 256, 0, stream>>>(ei1, cnt);
    kc_blocksum<<<SCAN_NB, 256, 0, stream>>>(cnt, bsum);
    kc_scanbsum<<<1, 256, 0, stream>>>(bsum, bofs);
    kc_apply<<<SCAN_NB, 256, 0, stream>>>(cnt, bofs, rowptr, cur);
    kc_scatter<<<(E_EDGES + 255) / 256, 256, 0, stream>>>(ei0, ei1, cur, srcs);

    // ---------------- Layer 1: x[N,16] -> bufB[N,128] (ELU) ----------------
    k1_gemm_alpha<NFEAT, HC, HEADS><<<(N_NODES + 7) / 8, 256, 0, stream>>>(
        x, W1, aS1, aD1, bufA, asrc, adst, N_NODES);
    k_aggr<HEADS, HID, true><<<(N_NODES + 3) / 4, 256, 0, stream>>>(
        asrc, adst, bufA, rowptr, cnt, srcs, b1, bufB);

    // ---------------- Layer 2: bufB[N,128] -> bufB[N,128] (ELU) ----------------
    k1_gemm_alpha<HC, HC, HEADS><<<(N_NODES + 7) / 8, 256, 0, stream>>>(
        bufB, W2, aS2, aD2, bufA, asrc, adst, N_NODES);
    k_aggr<HEADS, HID, true><<<(N_NODES + 3) / 4, 256, 0, stream>>>(
        asrc, adst, bufA, rowptr, cnt, srcs, b2, bufB);

    // ---------------- Layer 3: bufB[N,128] -> bufB[N,32] (no act, H=1) ----------------
    k1_gemm_alpha<HC, HID, 1><<<(N_NODES + 31) / 32, 256, 0, stream>>>(
        bufB, W3, aS3, aD3, bufA, asrc, adst, N_NODES);
    k_aggr<1, HID, false><<<(N_NODES + 15) / 16, 256, 0, stream>>>(
        asrc, adst, bufA, rowptr, cnt, srcs, b3, bufB);

    // ---------------- Edge MLP: node precompute, then per-edge ----------------
    float* P = bufA;   // bufA free after layer 3
    k5a_precomp<<<(N_NODES + 15) / 16, 256, 0, stream>>>(bufB, Wm1, P);
    k5b_mlp<<<(E_EDGES + 255) / 256, 256, 0, stream>>>(
        ei0, ei1, P, ea, Wm1, bm1, Wm2, bm2, Wm3, bm3, out);
}

// Round 8
// 452.373 us; speedup vs baseline: 1.9238x; 1.0367x over previous
//
#include <hip/hip_runtime.h>
#include <hip/hip_bf16.h>
#include <math.h>

#define N_NODES 50000
#define E_EDGES 800000
#define NFEAT 16
#define EFEAT 8
#define HID 32
#define HEADS 4
#define HC 128
#define SCAN_NB ((N_NODES + 255) / 256)   // 196

typedef float f4v __attribute__((ext_vector_type(4)));

__device__ __forceinline__ float lrelu(float v) { return v > 0.f ? v : 0.2f * v; }
__device__ __forceinline__ float bflo(unsigned u) { return __uint_as_float(u << 16); }
__device__ __forceinline__ float bfhi(unsigned u) { return __uint_as_float(u & 0xffff0000u); }

// ---- K1: h = x @ W ; alpha_src/dst = einsum(h, aS/aD) per head ----
template<int FIN, int HOUT, int H>
__global__ void k1_gemm_alpha(const float* __restrict__ x, const float* __restrict__ W,
                              const float* __restrict__ aS, const float* __restrict__ aD,
                              float* __restrict__ hout, float* __restrict__ asrc,
                              float* __restrict__ adst, int n_nodes)
{
    constexpr int GROUPS = 256 / HOUT;
    constexpr int NPT = 4;
    constexpr int NPB = GROUPS * NPT;
    __shared__ float xs[NPB * (FIN + 1)];
    const int tid = threadIdx.x;
    const int nb0 = blockIdx.x * NPB;
    for (int idx = tid; idx < NPB * FIN; idx += 256) {
        int node = idx / FIN, k = idx % FIN;
        int gn = nb0 + node;
        xs[node * (FIN + 1) + k] = (gn < n_nodes) ? x[gn * FIN + k] : 0.f;
    }
    __syncthreads();
    const int c = tid % HOUT;
    const int g = tid / HOUT;
    const int head = c / HID;
    const int cc = c % HID;
    const float aSv = aS[head * HID + cc];
    const float aDv = aD[head * HID + cc];
    float acc[NPT];
#pragma unroll
    for (int i = 0; i < NPT; i++) acc[i] = 0.f;
    for (int k = 0; k < FIN; k++) {
        float w = W[k * HOUT + c];
#pragma unroll
        for (int i = 0; i < NPT; i++)
            acc[i] += w * xs[(g * NPT + i) * (FIN + 1) + k];
    }
#pragma unroll
    for (int i = 0; i < NPT; i++) {
        int n = nb0 + g * NPT + i;
        bool ok = (n < n_nodes);
        float h = acc[i];
        if (ok) hout[n * HOUT + c] = h;
        float pa = h * aSv, pb = h * aDv;
#pragma unroll
        for (int off = 16; off >= 1; off >>= 1) {
            pa += __shfl_xor(pa, off, 32);
            pb += __shfl_xor(pb, off, 32);
        }
        if (ok && cc == 0) { asrc[n * H + head] = pa; adst[n * H + head] = pb; }
    }
}

// ---- CSR build: histogram -> 3-phase scan -> scatter ----
__global__ void kc_count(const int* __restrict__ ei1, int* __restrict__ cnt)
{
    int e = blockIdx.x * 256 + threadIdx.x;
    if (e >= E_EDGES) return;
    atomicAdd(&cnt[ei1[e]], 1);
}

__global__ __launch_bounds__(256) void kc_blocksum(const int* __restrict__ cnt,
                                                   int* __restrict__ bsum)
{
    __shared__ int sd[256];
    const int tid = threadIdx.x;
    int i = blockIdx.x * 256 + tid;
    int v = (i < N_NODES) ? cnt[i] : 0;
    sd[tid] = v;
    __syncthreads();
    for (int off = 128; off >= 1; off >>= 1) {
        if (tid < off) sd[tid] += sd[tid + off];
        __syncthreads();
    }
    if (tid == 0) bsum[blockIdx.x] = sd[0];
}

__global__ __launch_bounds__(256) void kc_scanbsum(const int* __restrict__ bsum,
                                                   int* __restrict__ bofs)
{
    __shared__ int sd[256];
    const int tid = threadIdx.x;
    int v = (tid < SCAN_NB) ? bsum[tid] : 0;
    sd[tid] = v;
    __syncthreads();
    for (int off = 1; off < 256; off <<= 1) {
        int u = (tid >= off) ? sd[tid - off] : 0;
        __syncthreads();
        sd[tid] += u;
        __syncthreads();
    }
    if (tid < SCAN_NB) bofs[tid] = sd[tid] - v;
}

__global__ __launch_bounds__(256) void kc_apply(const int* __restrict__ cnt,
                                                const int* __restrict__ bofs,
                                                int* __restrict__ rowptr,
                                                int* __restrict__ cur)
{
    __shared__ int sd[256];
    const int tid = threadIdx.x;
    int i = blockIdx.x * 256 + tid;
    int v = (i < N_NODES) ? cnt[i] : 0;
    sd[tid] = v;
    __syncthreads();
    for (int off = 1; off < 256; off <<= 1) {
        int u = (tid >= off) ? sd[tid - off] : 0;
        __syncthreads();
        sd[tid] += u;
        __syncthreads();
    }
    int excl = sd[tid] - v + bofs[blockIdx.x];
    if (i < N_NODES) { rowptr[i] = excl; cur[i] = excl; }
}

__global__ void kc_scatter(const int* __restrict__ ei0, const int* __restrict__ ei1,
                           int* __restrict__ cur, int* __restrict__ srcs)
{
    int e = blockIdx.x * 256 + threadIdx.x;
    if (e >= E_EDGES) return;
    int pos = atomicAdd(&cur[ei1[e]], 1);
    srcs[pos] = ei0[e];
}

// ---- fused aggregation: online segment-softmax + weighted sum + bias (+ELU) ----
template<int H, int C, bool DO_ELU>
__global__ __launch_bounds__(256) void k_aggr(
    const float* __restrict__ asrc, const float* __restrict__ adst,
    const float* __restrict__ hbuf, const int* __restrict__ rowptr,
    const int* __restrict__ deg, const int* __restrict__ srcs,
    const float* __restrict__ b, float* __restrict__ outp)
{
    constexpr int HCL = H * C;
    constexpr int TPE = HCL / 2;
    constexpr int NPB = 256 / TPE;
    const int t = threadIdx.x % TPE;
    const int n = blockIdx.x * NPB + threadIdx.x / TPE;
    if (n >= N_NODES) return;
    const int c0 = 2 * t;
    const int head = c0 / C;
    const float adstv = adst[n * H + head];
    // init with self-loop
    float m = lrelu(asrc[n * H + head] + adstv);
    float ssum = 1.f;
    float2 hv = *(const float2*)(hbuf + (size_t)n * HCL + c0);
    float a0 = hv.x, a1 = hv.y;
    const int base = rowptr[n];
    const int dg = deg[n];
    int i = 0;
    for (; i + 4 <= dg; i += 4) {
        int s0 = srcs[base + i + 0];
        int s1 = srcs[base + i + 1];
        int s2 = srcs[base + i + 2];
        int s3 = srcs[base + i + 3];
        float sc0 = lrelu(asrc[s0 * H + head] + adstv);
        float sc1 = lrelu(asrc[s1 * H + head] + adstv);
        float sc2 = lrelu(asrc[s2 * H + head] + adstv);
        float sc3 = lrelu(asrc[s3 * H + head] + adstv);
        float2 h0 = *(const float2*)(hbuf + (size_t)s0 * HCL + c0);
        float2 h1 = *(const float2*)(hbuf + (size_t)s1 * HCL + c0);
        float2 h2 = *(const float2*)(hbuf + (size_t)s2 * HCL + c0);
        float2 h3v = *(const float2*)(hbuf + (size_t)s3 * HCL + c0);
        float sc[4] = {sc0, sc1, sc2, sc3};
        float2 hh[4] = {h0, h1, h2, h3v};
#pragma unroll
        for (int u = 0; u < 4; u++) {
            float scv = sc[u];
            float ex;
            if (scv > m) {
                float r = __expf(m - scv);
                ssum *= r; a0 *= r; a1 *= r;
                m = scv;
                ex = 1.f;
            } else {
                ex = __expf(scv - m);
            }
            ssum += ex;
            a0 += ex * hh[u].x;
            a1 += ex * hh[u].y;
        }
    }
    for (; i < dg; i++) {
        int s = srcs[base + i];
        float sc = lrelu(asrc[s * H + head] + adstv);
        float2 hs = *(const float2*)(hbuf + (size_t)s * HCL + c0);
        float ex;
        if (sc > m) {
            float r = __expf(m - sc);
            ssum *= r; a0 *= r; a1 *= r;
            m = sc;
            ex = 1.f;
        } else {
            ex = __expf(sc - m);
        }
        ssum += ex;
        a0 += ex * hs.x;
        a1 += ex * hs.y;
    }
    float inv = 1.f / (ssum + 1e-16f);
    float v0 = a0 * inv + b[c0];
    float v1 = a1 * inv + b[c0 + 1];
    if (DO_ELU) {
        v0 = v0 > 0.f ? v0 : __expf(v0) - 1.f;
        v1 = v1 > 0.f ? v1 : __expf(v1) - 1.f;
    }
    *(float2*)(outp + (size_t)n * HCL + c0) = make_float2(v0, v1);
}

// ---- K5a: node-level precompute for MLP layer 1 (bf16 output) ----
// Pb[n][0:32]  = h3[n] @ W1a   (Wm1 rows 0..31)
// Pb[n][32:64] = h3[n] @ W1b   (Wm1 rows 32..63)
__global__ __launch_bounds__(256) void k5a_precomp(
    const float* __restrict__ h3, const float* __restrict__ Wm1,
    __hip_bfloat16* __restrict__ Pb)
{
    __shared__ float w[64 * 32];      // rows 0..63 of Wm1
    __shared__ float hsh[16][33];
    const int tid = threadIdx.x;
    for (int i = tid; i < 64 * 32; i += 256) w[i] = Wm1[i];
    const int nb0 = blockIdx.x * 16;
    for (int idx = tid; idx < 16 * 32; idx += 256) {
        int node = idx / 32, k = idx % 32;
        int gn = nb0 + node;
        hsh[node][k] = (gn < N_NODES) ? h3[gn * 32 + k] : 0.f;
    }
    __syncthreads();
    const int c = tid % 64;           // output channel 0..63
    const int part = c / 32;          // 0 -> W1a, 1 -> W1b
    const int j = c % 32;
    for (int ln = tid / 64; ln < 16; ln += 4) {
        int gn = nb0 + ln;
        if (gn >= N_NODES) break;
        float sum = 0.f;
#pragma unroll
        for (int k = 0; k < 32; k++)
            sum += hsh[ln][k] * w[(part * 32 + k) * 32 + j];
        Pb[(size_t)gn * 64 + c] = __float2bfloat16(sum);
    }
}

// ---- K5b: per-edge MLP using precomputed bf16 P ----
__global__ __launch_bounds__(256) void k5b_mlp(
                       const int* __restrict__ ei0, const int* __restrict__ ei1,
                       const __hip_bfloat16* __restrict__ Pb, const float* __restrict__ ea,
                       const float* __restrict__ Wm1, const float* __restrict__ bm1,
                       const float* __restrict__ Wm2, const float* __restrict__ bm2,
                       const float* __restrict__ Wm3, const float* __restrict__ bm3,
                       float* __restrict__ out)
{
    __shared__ float w1c[8 * 32], w2[32 * 32], w3s[32], b1s[32], b2s[32];
    __shared__ float b3s;
    const int tid = threadIdx.x;
    if (tid < 8 * 32) w1c[tid] = Wm1[64 * 32 + tid];
    for (int i = tid; i < 32 * 32; i += 256) w2[i] = Wm2[i];
    if (tid < 32) { w3s[tid] = Wm3[tid]; b1s[tid] = bm1[tid]; b2s[tid] = bm2[tid]; }
    if (tid == 0) b3s = bm3[0];
    __syncthreads();
    const int e = blockIdx.x * 256 + tid;
    if (e >= E_EDGES) return;
    const int s = ei0[e], d = ei1[e];

    float z1[32];
#pragma unroll
    for (int j = 0; j < 32; j++) z1[j] = b1s[j];

    // edge_attr contribution (8x32 matmul) — non-temporal: streamed once
    const f4v* eav = (const f4v*)(ea + (size_t)e * 8);
#pragma unroll
    for (int kq = 0; kq < 2; kq++) {
        f4v v = __builtin_nontemporal_load(&eav[kq]);
        const float* wrow = &w1c[(kq * 4) * 32];
#pragma unroll
        for (int j = 0; j < 32; j++) z1[j] += v.x * wrow[0 * 32 + j];
#pragma unroll
        for (int j = 0; j < 32; j++) z1[j] += v.y * wrow[1 * 32 + j];
#pragma unroll
        for (int j = 0; j < 32; j++) z1[j] += v.z * wrow[2 * 32 + j];
#pragma unroll
        for (int j = 0; j < 32; j++) z1[j] += v.w * wrow[3 * 32 + j];
    }
    // node contributions: one 64B line per side (bf16), want these L2-cached
    const uint4* ps4 = (const uint4*)(Pb + (size_t)s * 64);
    const uint4* pd4 = (const uint4*)(Pb + (size_t)d * 64 + 32);
#pragma unroll
    for (int q = 0; q < 4; q++) {
        uint4 a = ps4[q];
        uint4 b = pd4[q];
        z1[8 * q + 0] += bflo(a.x) + bflo(b.x);
        z1[8 * q + 1] += bfhi(a.x) + bfhi(b.x);
        z1[8 * q + 2] += bflo(a.y) + bflo(b.y);
        z1[8 * q + 3] += bfhi(a.y) + bfhi(b.y);
        z1[8 * q + 4] += bflo(a.z) + bflo(b.z);
        z1[8 * q + 5] += bfhi(a.z) + bfhi(b.z);
        z1[8 * q + 6] += bflo(a.w) + bflo(b.w);
        z1[8 * q + 7] += bfhi(a.w) + bfhi(b.w);
    }
#pragma unroll
    for (int j = 0; j < 32; j++) z1[j] = z1[j] > 0.f ? z1[j] : 0.f;

    float z3 = b3s;
#pragma unroll
    for (int j = 0; j < 32; j++) {
        float a = b2s[j];
#pragma unroll
        for (int k = 0; k < 32; k++) a += z1[k] * w2[k * 32 + j];
        z3 += (a > 0.f ? a : 0.f) * w3s[j];
    }
    float r = (z3 > 20.f) ? z3 : log1pf(__expf(z3));
    __builtin_nontemporal_store(r, &out[e]);
}

extern "C" void kernel_launch(void* const* d_in, const int* in_sizes, int n_in,
                              void* d_out, int out_size, void* d_ws, size_t ws_size,
                              hipStream_t stream)
{
    const float* x   = (const float*)d_in[0];
    const int*   ei  = (const int*)d_in[1];
    const int*   ei0 = ei;
    const int*   ei1 = ei + E_EDGES;
    const float* ea  = (const float*)d_in[2];
    const float* W1  = (const float*)d_in[3];
    const float* aS1 = (const float*)d_in[4];
    const float* aD1 = (const float*)d_in[5];
    const float* b1  = (const float*)d_in[6];
    const float* W2  = (const float*)d_in[7];
    const float* aS2 = (const float*)d_in[8];
    const float* aD2 = (const float*)d_in[9];
    const float* b2  = (const float*)d_in[10];
    const float* W3  = (const float*)d_in[11];
    const float* aS3 = (const float*)d_in[12];
    const float* aD3 = (const float*)d_in[13];
    const float* b3  = (const float*)d_in[14];
    const float* Wm1 = (const float*)d_in[15];
    const float* bm1 = (const float*)d_in[16];
    const float* Wm2 = (const float*)d_in[17];
    const float* bm2 = (const float*)d_in[18];
    const float* Wm3 = (const float*)d_in[19];
    const float* bm3 = (const float*)d_in[20];

    float* ws = (float*)d_ws;
    float* bufA = ws;                                    // [N,128] h / later Pb[N,64] bf16
    float* bufB = bufA + (size_t)N_NODES * HC;           // [N,128] layer output
    float* asrc = bufB + (size_t)N_NODES * HC;           // [N,4]
    float* adst = asrc + (size_t)N_NODES * HEADS;        // [N,4]
    int* cnt    = (int*)(adst + (size_t)N_NODES * HEADS);// [N] in-degree (no self-loop)
    int* rowptr = cnt + N_NODES;                         // [N]
    int* cur    = rowptr + N_NODES;                      // [N]
    int* srcs   = cur + N_NODES;                         // [E]
    int* bsum   = srcs + E_EDGES;                        // [SCAN_NB]
    int* bofs   = bsum + 256;                            // [SCAN_NB]

    float* out = (float*)d_out;

    // ---------------- CSR build (once; shared by all 3 layers) ----------------
    hipMemsetAsync(cnt, 0, (size_t)N_NODES * sizeof(int), stream);
    kc_count<<<(E_EDGES + 255) / 256, 256, 0, stream>>>(ei1, cnt);
    kc_blocksum<<<SCAN_NB, 256, 0, stream>>>(cnt, bsum);
    kc_scanbsum<<<1, 256, 0, stream>>>(bsum, bofs);
    kc_apply<<<SCAN_NB, 256, 0, stream>>>(cnt, bofs, rowptr, cur);
    kc_scatter<<<(E_EDGES + 255) / 256, 256, 0, stream>>>(ei0, ei1, cur, srcs);

    // ---------------- Layer 1: x[N,16] -> bufB[N,128] (ELU) ----------------
    k1_gemm_alpha<NFEAT, HC, HEADS><<<(N_NODES + 7) / 8, 256, 0, stream>>>(
        x, W1, aS1, aD1, bufA, asrc, adst, N_NODES);
    k_aggr<HEADS, HID, true><<<(N_NODES + 3) / 4, 256, 0, stream>>>(
        asrc, adst, bufA, rowptr, cnt, srcs, b1, bufB);

    // ---------------- Layer 2: bufB[N,128] -> bufB[N,128] (ELU) ----------------
    k1_gemm_alpha<HC, HC, HEADS><<<(N_NODES + 7) / 8, 256, 0, stream>>>(
        bufB, W2, aS2, aD2, bufA, asrc, adst, N_NODES);
    k_aggr<HEADS, HID, true><<<(N_NODES + 3) / 4, 256, 0, stream>>>(
        asrc, adst, bufA, rowptr, cnt, srcs, b2, bufB);

    // ---------------- Layer 3: bufB[N,128] -> bufB[N,32] (no act, H=1) ----------------
    k1_gemm_alpha<HC, HID, 1><<<(N_NODES + 31) / 32, 256, 0, stream>>>(
        bufB, W3, aS3, aD3, bufA, asrc, adst, N_NODES);
    k_aggr<1, HID, false><<<(N_NODES + 15) / 16, 256, 0, stream>>>(
        asrc, adst, bufA, rowptr, cnt, srcs, b3, bufB);

    // ---------------- Edge MLP: node precompute (bf16), then per-edge ----------------
    __hip_bfloat16* Pb = (__hip_bfloat16*)bufA;   // bufA free after layer 3
    k5a_precomp<<<(N_NODES + 15) / 16, 256, 0, stream>>>(bufB, Wm1, Pb);
    k5b_mlp<<<(E_EDGES + 255) / 256, 256, 0, stream>>>(
        ei0, ei1, Pb, ea, Wm1, bm1, Wm2, bm2, Wm3, bm3, out);
}